// Round 4
// baseline (187.584 us; speedup 1.0000x reference)
//
#include <hip/hip_runtime.h>
#include <hip/hip_bf16.h>

// Problem constants
#define NA 1024   // n_atom
#define NT 256    // n_token
#define CS 384    // c_s
#define CZ 128    // c_z
#define CA 128    // c_atom
#define CP 16     // c_atom_pair

typedef __attribute__((ext_vector_type(8))) short short8;
typedef __attribute__((ext_vector_type(4))) float f32x4;
typedef __attribute__((ext_vector_type(4))) unsigned int u32x4;

__device__ __forceinline__ float bflo(unsigned u){ return __uint_as_float(u << 16); }
__device__ __forceinline__ float bfhi(unsigned u){ return __uint_as_float(u & 0xffff0000u); }
__device__ __forceinline__ float bfu(unsigned short v){ return __uint_as_float(((unsigned)v) << 16); }
__device__ __forceinline__ unsigned short f2bf(float f){
  unsigned u = __float_as_uint(f);
  return (unsigned short)((u + 0x7fffu + ((u >> 16) & 1u)) >> 16); // RNE
}
__device__ __forceinline__ unsigned pack2(float lo, float hi){
  return (unsigned)f2bf(lo) | ((unsigned)f2bf(hi) << 16);
}

__device__ __forceinline__ int lbound(const unsigned short* tokL, int key){
  int lo = 0, hi = NA;
  while (lo < hi) { int mid = (lo + hi) >> 1; if ((int)tokL[mid] < key) lo = mid + 1; else hi = mid; }
  return lo;
}

// ===========================================================================
// PATH A (ws_size >= 2,164,736 B): materialize w_tm, then pure streaming pass.
// ws layout: tok16 [1024 u16]   bytes [0, 2048)
//            ytok  [32768 bf16]  bytes [2048, 67584)
//            w_tm  [1048576 bf16] bytes [67584, 2164736)
// R8: no nontemporal hints — harness keeps plm/out L2/L3-hot.
// R9: lane-major chunk mapping (unit-stride 1-KB wave segments). WIN (~4 µs).
// R10: 8 chunks/thread + tok16 LDS slice — NULL.
// R11: wtm row staged in LDS — NULL/slightly worse. Post-mortem: atoms are
// SORTED by token, so tb is non-decreasing across a wave and the global wtm
// gather was already a near-sequential 32-B-row walk. The LDS stage fixed a
// non-problem and added a barrier.
// R12: copy-kernel shape. Persistent 2048 blocks, 8 lane-major chunks/thread,
// ALL loads issued before any store (24+ VMEM in flight/thread), no barrier,
// no LDS, global near-sequential gather. This is the last structural family;
// if it lands at 40±2 µs like the other three, stream is at its achievable
// mixed-stream rate (135 MB mandatory @ ~6.3 TB/s sum ceiling = 21 µs ideal,
// ~3.3 TB/s achieved is then the pattern's real ceiling, not fixable).
// ===========================================================================

// prep_full: blocks [0,256)    role A: tok16[a] (wave per atom)
//            blocks [256,512)  role B: ytok[t,:] = LN_s(s_trunk[t])@W_s (bf16)
//            blocks [512,1536) role C: w_tm[t,m,:] = LN_z(zij[t,m])@W_z (bf16, MFMA)
__global__ __launch_bounds__(256) void prep_full_kernel(
    const float* __restrict__ a2t,
    const float* __restrict__ s_trunk,
    const float* __restrict__ lnsw,
    const float* __restrict__ lnsb,
    const float* __restrict__ Ws,
    const float* __restrict__ zij,
    const float* __restrict__ lnzw,
    const float* __restrict__ lnzb,
    const float* __restrict__ Wz,
    unsigned short* __restrict__ tok16,
    unsigned short* __restrict__ ytok,
    unsigned short* __restrict__ wtm)
{
  __shared__ float redS[4], redQ[4];
  __shared__ float lnbuf[CS];
  __shared__ float part[CA];
  __shared__ __align__(16) unsigned short stage[4 * 16 * 136]; // 17.4 KB

  const int blk  = blockIdx.x;
  const int tid  = threadIdx.x;
  const int lane = tid & 63;
  const int wv   = tid >> 6;

  if (blk < 256) {
    // ---- role A ----
    int a = blk * 4 + wv;
    float4 u = ((const float4*)(a2t + (size_t)a * NT))[lane];
    bool hit = (u.x != 0.f) | (u.y != 0.f) | (u.z != 0.f) | (u.w != 0.f);
    unsigned long long m = __ballot(hit);
    int fl = __ffsll(m) - 1;
    if (lane == fl) {
      int t = lane * 4;
      if (u.x != 0.f)      { }
      else if (u.y != 0.f) t += 1;
      else if (u.z != 0.f) t += 2;
      else                 t += 3;
      tok16[a] = (unsigned short)t;
    }
  } else if (blk < 512) {
    // ---- role B ----
    int tk = blk - 256;
    float f0 = 0.f, f1 = 0.f;
    if (tid < 192) {
      float2 v = ((const float2*)(s_trunk + (size_t)tk * CS))[tid];
      f0 = v.x; f1 = v.y;
    }
    float s = f0 + f1;
    float q = f0 * f0 + f1 * f1;
    #pragma unroll
    for (int m = 1; m < 64; m <<= 1) { s += __shfl_xor(s, m); q += __shfl_xor(q, m); }
    if (lane == 0) { redS[wv] = s; redQ[wv] = q; }
    __syncthreads();
    if (tid == 0) {
      float S = redS[0] + redS[1] + redS[2] + redS[3];
      float Q = redQ[0] + redQ[1] + redQ[2] + redQ[3];
      float mean = S * (1.f / 384.f);
      float var  = Q * (1.f / 384.f) - mean * mean;
      redS[0] = mean;
      redQ[0] = rsqrtf(var + 1e-5f);
    }
    __syncthreads();
    float mean = redS[0], rstd = redQ[0];
    if (tid < 192) {
      float2 w2 = ((const float2*)lnsw)[tid];
      float2 b2 = ((const float2*)lnsb)[tid];
      lnbuf[2 * tid]     = fmaf((f0 - mean) * rstd, w2.x, b2.x);
      lnbuf[2 * tid + 1] = fmaf((f1 - mean) * rstd, w2.y, b2.y);
    }
    __syncthreads();
    int j = tid & 127, half = tid >> 7;
    float acc = 0.f;
    int c0 = half * 192;
    #pragma unroll 8
    for (int c = c0; c < c0 + 192; ++c)
      acc = fmaf(lnbuf[c], Ws[(size_t)c * CA + j], acc);
    if (half) part[j] = acc;
    __syncthreads();
    if (!half) ytok[(size_t)tk * CA + j] = f2bf(acc + part[j]);
  } else {
    // ---- role C: wave = 16 rows of the 65536 (t*256+m) rows ----
    int cb = blk - 512;
    int r = lane >> 2, q = lane & 3;       // 4 lanes per row, 32 channels each
    int rowbase = cb * 64 + wv * 16;
    const float4* zp = (const float4*)(zij + (size_t)(rowbase + r) * CZ + q * 32);
    float x[32];
    float sm = 0.f, ss = 0.f;
    #pragma unroll
    for (int i = 0; i < 8; ++i) {
      float4 v = zp[i];
      x[4 * i]     = v.x; x[4 * i + 1] = v.y;
      x[4 * i + 2] = v.z; x[4 * i + 3] = v.w;
      sm += (v.x + v.y) + (v.z + v.w);
      ss = fmaf(v.x, v.x, ss); ss = fmaf(v.y, v.y, ss);
      ss = fmaf(v.z, v.z, ss); ss = fmaf(v.w, v.w, ss);
    }
    sm += __shfl_xor(sm, 1); sm += __shfl_xor(sm, 2);
    ss += __shfl_xor(ss, 1); ss += __shfl_xor(ss, 2);
    float mean = sm * (1.f / 128.f);
    float var  = ss * (1.f / 128.f) - mean * mean;
    float rstd = rsqrtf(var + 1e-5f);
    unsigned short* st = stage + wv * 2176 + r * 136 + q * 32;
    const float4* lwp = (const float4*)(lnzw + q * 32);
    const float4* lbp = (const float4*)(lnzb + q * 32);
    #pragma unroll
    for (int i = 0; i < 4; ++i) {
      float4 lw0 = lwp[2 * i], lw1 = lwp[2 * i + 1];
      float4 lb0 = lbp[2 * i], lb1 = lbp[2 * i + 1];
      int c = i * 8;
      unsigned o0 = pack2(fmaf((x[c]     - mean) * rstd, lw0.x, lb0.x),
                          fmaf((x[c + 1] - mean) * rstd, lw0.y, lb0.y));
      unsigned o1 = pack2(fmaf((x[c + 2] - mean) * rstd, lw0.z, lb0.z),
                          fmaf((x[c + 3] - mean) * rstd, lw0.w, lb0.w));
      unsigned o2 = pack2(fmaf((x[c + 4] - mean) * rstd, lw1.x, lb1.x),
                          fmaf((x[c + 5] - mean) * rstd, lw1.y, lb1.y));
      unsigned o3 = pack2(fmaf((x[c + 6] - mean) * rstd, lw1.z, lb1.z),
                          fmaf((x[c + 7] - mean) * rstd, lw1.w, lb1.w));
      uint4 ov; ov.x = o0; ov.y = o1; ov.z = o2; ov.w = o3;
      ((uint4*)st)[i] = ov;
    }
    __syncthreads();
    // B fragment: B[k][n], n = lane&15, k = kk*32 + (lane>>4)*8 + j
    int h = lane >> 4, lm = lane & 15;
    short8 bfrag[4];
    #pragma unroll
    for (int kk = 0; kk < 4; ++kk)
      #pragma unroll
      for (int jj = 0; jj < 8; ++jj)
        bfrag[kk][jj] = (short)f2bf(Wz[(size_t)(kk * 32 + h * 8 + jj) * CP + lm]);
    const unsigned short* sb = stage + wv * 2176;
    f32x4 acc = {0.f, 0.f, 0.f, 0.f};
    #pragma unroll
    for (int kk = 0; kk < 4; ++kk) {
      short8 af = *(const short8*)(sb + lm * 136 + kk * 32 + h * 8); // A[m=lm][k]
      acc = __builtin_amdgcn_mfma_f32_16x16x32_bf16(af, bfrag[kk], acc, 0, 0, 0);
    }
    // C/D: col(n)=lane&15, row(m)=(lane>>4)*4+reg
    #pragma unroll
    for (int jj = 0; jj < 4; ++jj)
      wtm[(size_t)(rowbase + h * 4 + jj) * CP + lm] = f2bf(acc[jj]);
  }
}

// stream (R12, copy-shaped):
//   blocks [0,2048)    pair part. 8 lane-major f32x4 chunks per thread:
//                      pass pb = m*2048+blk (m=0..7), chunk c = pb*256+tid.
//                      atom a = pb>>4 (block-uniform), pair col b = (pb&15)*64
//                      + (tid>>2). All loads issued before any store; no
//                      barrier, no LDS. wtm gather is near-sequential because
//                      tok16 is sorted.
//   blocks [2048,2176) cl_out = cl + ytok[tok[a]]   (f32x4/thread)
//   blocks [2176,2304) ql_out = ql + rl @ W_r       (f32x4/thread)
__global__ __launch_bounds__(256) void stream_kernel(
    const float* __restrict__ cl,
    const float* __restrict__ plm,
    const float* __restrict__ ql,
    const float* __restrict__ rl,
    const float* __restrict__ Wr,
    const unsigned short* __restrict__ tok16,
    const unsigned short* __restrict__ ytok,
    const unsigned short* __restrict__ wtm,
    float* __restrict__ out)
{
  const int blk = blockIdx.x;
  const int tid = threadIdx.x;
  if (blk < 2048) {
    const int quar = tid & 3;     // f32x4 quarter of the 16-ch pair row
    const int g    = tid >> 2;    // pair-group 0..63 within a pass
    const f32x4* plm4 = (const f32x4*)plm;
    f32x4* out4 = (f32x4*)(out + (size_t)NA * CA);
    f32x4 p_[8];
    uint2 w_[8];
    int   c_[8];
    #pragma unroll
    for (int m = 0; m < 8; ++m) {
      const int pb = m * 2048 + blk;          // pass-block id, 0..16383
      const int c  = pb * 256 + tid;          // f32x4 chunk, unit-stride/wave
      const int a  = pb >> 4;                 // block-uniform atom row
      const int b  = ((pb & 15) << 6) + g;    // pair column (ascending w/ lane)
      const int ta = (int)tok16[a];
      const int tb = (int)tok16[b];           // non-decreasing across wave
      w_[m] = *(const uint2*)(wtm + ((((size_t)ta << 8) + (size_t)tb) << 4) + (quar << 2));
      p_[m] = plm4[c];
      c_[m] = c;
    }
    #pragma unroll
    for (int m = 0; m < 8; ++m) {
      f32x4 o;
      o.x = p_[m].x + bflo(w_[m].x);
      o.y = p_[m].y + bfhi(w_[m].x);
      o.z = p_[m].z + bflo(w_[m].y);
      o.w = p_[m].w + bfhi(w_[m].y);
      out4[c_[m]] = o;
    }
  } else if (blk < 2176) {
    // cl: 32768 f32x4 chunks
    int c = (blk - 2048) * 256 + tid;
    int aa = c >> 5, jq = c & 31;
    int ta = (int)tok16[aa];
    uint2 y = *(const uint2*)(ytok + (size_t)ta * CA + jq * 4);
    f32x4 v = ((const f32x4*)cl)[c];
    f32x4 o;
    o.x = v.x + bflo(y.x); o.y = v.y + bfhi(y.x);
    o.z = v.z + bflo(y.y); o.w = v.w + bfhi(y.y);
    ((f32x4*)out)[c] = o;
  } else {
    // ql: 32768 f32x4 chunks
    int c = (blk - 2176) * 256 + tid;
    int aa = c >> 5, j0 = (c & 31) * 4;
    float r0 = rl[aa * 3 + 0], r1 = rl[aa * 3 + 1], r2 = rl[aa * 3 + 2];
    f32x4 w0 = *(const f32x4*)(Wr + j0);
    f32x4 w1 = *(const f32x4*)(Wr + CA + j0);
    f32x4 w2 = *(const f32x4*)(Wr + 2 * CA + j0);
    f32x4 v = ((const f32x4*)ql)[c];
    f32x4 o;
    o.x = fmaf(r2, w2.x, fmaf(r1, w1.x, fmaf(r0, w0.x, v.x)));
    o.y = fmaf(r2, w2.y, fmaf(r1, w1.y, fmaf(r0, w0.y, v.y)));
    o.z = fmaf(r2, w2.z, fmaf(r1, w1.z, fmaf(r0, w0.z, v.z)));
    o.w = fmaf(r2, w2.w, fmaf(r1, w1.w, fmaf(r0, w0.w, v.w)));
    ((f32x4*)out)[((size_t)NA * CA + (size_t)NA * NA * CP) / 4 + c] = o;
  }
}

// ===========================================================================
// PATH B (fallback, small ws): Round-4 kernels, proven correct at 66 KB ws.
// ===========================================================================
__global__ __launch_bounds__(256) void prep_kernel(
    const float* __restrict__ a2t,
    const float* __restrict__ s_trunk,
    const float* __restrict__ lnsw,
    const float* __restrict__ lnsb,
    const float* __restrict__ Ws,
    unsigned short* __restrict__ tok16,
    unsigned short* __restrict__ ytok)
{
  __shared__ float redS[4], redQ[4];
  __shared__ float lnbuf[CS];
  __shared__ float part[CA];

  const int blk  = blockIdx.x;
  const int tid  = threadIdx.x;
  const int lane = tid & 63;
  const int wv   = tid >> 6;

  if (blk < 256) {
    int a = blk * 4 + wv;
    float4 u = ((const float4*)(a2t + (size_t)a * NT))[lane];
    bool hit = (u.x != 0.f) | (u.y != 0.f) | (u.z != 0.f) | (u.w != 0.f);
    unsigned long long m = __ballot(hit);
    int fl = __ffsll(m) - 1;
    if (lane == fl) {
      int t = lane * 4;
      if (u.x != 0.f)      { }
      else if (u.y != 0.f) t += 1;
      else if (u.z != 0.f) t += 2;
      else                 t += 3;
      tok16[a] = (unsigned short)t;
    }
  } else {
    int tk = blk - 256;
    float f0 = 0.f, f1 = 0.f;
    if (tid < 192) {
      float2 v = ((const float2*)(s_trunk + (size_t)tk * CS))[tid];
      f0 = v.x; f1 = v.y;
    }
    float s = f0 + f1;
    float q = f0 * f0 + f1 * f1;
    #pragma unroll
    for (int m = 1; m < 64; m <<= 1) { s += __shfl_xor(s, m); q += __shfl_xor(q, m); }
    if (lane == 0) { redS[wv] = s; redQ[wv] = q; }
    __syncthreads();
    if (tid == 0) {
      float S = redS[0] + redS[1] + redS[2] + redS[3];
      float Q = redQ[0] + redQ[1] + redQ[2] + redQ[3];
      float mean = S * (1.f / 384.f);
      float var  = Q * (1.f / 384.f) - mean * mean;
      redS[0] = mean;
      redQ[0] = rsqrtf(var + 1e-5f);
    }
    __syncthreads();
    float mean = redS[0], rstd = redQ[0];
    if (tid < 192) {
      float2 w2 = ((const float2*)lnsw)[tid];
      float2 b2 = ((const float2*)lnsb)[tid];
      lnbuf[2 * tid]     = fmaf((f0 - mean) * rstd, w2.x, b2.x);
      lnbuf[2 * tid + 1] = fmaf((f1 - mean) * rstd, w2.y, b2.y);
    }
    __syncthreads();
    int j = tid & 127, half = tid >> 7;
    float acc = 0.f;
    int c0 = half * 192;
    #pragma unroll 8
    for (int c = c0; c < c0 + 192; ++c)
      acc = fmaf(lnbuf[c], Ws[(size_t)c * CA + j], acc);
    if (half) part[j] = acc;
    __syncthreads();
    if (!half) ytok[(size_t)tk * CA + j] = f2bf(acc + part[j]);
  }
}

__global__ __launch_bounds__(256) void main_kernel(
    const float* __restrict__ cl,
    const float* __restrict__ plm,
    const float* __restrict__ ql,
    const float* __restrict__ rl,
    const float* __restrict__ Wr,
    const float* __restrict__ zij,
    const float* __restrict__ lnzw,
    const float* __restrict__ lnzb,
    const float* __restrict__ Wz,
    const unsigned short* __restrict__ tok16,
    const unsigned short* __restrict__ ytok,
    float* __restrict__ out)
{
  const int blk = blockIdx.x;
  const int tid = threadIdx.x;

  if (blk < 2048) {
    __shared__ unsigned short tokL[NA];
    __shared__ __align__(16) unsigned short ubuf[4 * 16 * 136];
    unsigned short* stage = ubuf;
    float* wlds = (float*)ubuf;

    const int lane = tid & 63;
    const int wv   = tid >> 6;
    const int t    = blk >> 3;
    const int m0   = ((blk >> 1) & 3) << 6;
    const int slot = blk & 1;

    ((uint2*)tokL)[tid] = ((const uint2*)tok16)[tid];
    __syncthreads();

    int s = lbound(tokL, t);
    int e = lbound(tokL, t + 1);
    if (s + slot >= e) return;
    int S = lbound(tokL, m0);
    int E = lbound(tokL, m0 + 64);
    if (S == E) return;

    {
      int r = lane >> 2, q = lane & 3;
      int mrow = m0 + wv * 16 + r;
      const float4* zp = (const float4*)(zij + ((size_t)t * NT + mrow) * CZ + q * 32);
      float x[32];
      float sm = 0.f, ss = 0.f;
      #pragma unroll
      for (int i = 0; i < 8; ++i) {
        float4 v = zp[i];
        x[4 * i]     = v.x; x[4 * i + 1] = v.y;
        x[4 * i + 2] = v.z; x[4 * i + 3] = v.w;
        sm += (v.x + v.y) + (v.z + v.w);
        ss = fmaf(v.x, v.x, ss); ss = fmaf(v.y, v.y, ss);
        ss = fmaf(v.z, v.z, ss); ss = fmaf(v.w, v.w, ss);
      }
      sm += __shfl_xor(sm, 1); sm += __shfl_xor(sm, 2);
      ss += __shfl_xor(ss, 1); ss += __shfl_xor(ss, 2);
      float mean = sm * (1.f / 128.f);
      float var  = ss * (1.f / 128.f) - mean * mean;
      float rstd = rsqrtf(var + 1e-5f);
      unsigned short* st = stage + wv * 2176 + r * 136 + q * 32;
      const float4* lwp = (const float4*)(lnzw + q * 32);
      const float4* lbp = (const float4*)(lnzb + q * 32);
      #pragma unroll
      for (int i = 0; i < 4; ++i) {
        float4 lw0 = lwp[2 * i], lw1 = lwp[2 * i + 1];
        float4 lb0 = lbp[2 * i], lb1 = lbp[2 * i + 1];
        int c = i * 8;
        unsigned o0 = pack2(fmaf((x[c]     - mean) * rstd, lw0.x, lb0.x),
                            fmaf((x[c + 1] - mean) * rstd, lw0.y, lb0.y));
        unsigned o1 = pack2(fmaf((x[c + 2] - mean) * rstd, lw0.z, lb0.z),
                            fmaf((x[c + 3] - mean) * rstd, lw0.w, lb0.w));
        unsigned o2 = pack2(fmaf((x[c + 4] - mean) * rstd, lw1.x, lb1.x),
                            fmaf((x[c + 5] - mean) * rstd, lw1.y, lb1.y));
        unsigned o3 = pack2(fmaf((x[c + 6] - mean) * rstd, lw1.z, lb1.z),
                            fmaf((x[c + 7] - mean) * rstd, lw1.w, lb1.w));
        uint4 ov; ov.x = o0; ov.y = o1; ov.z = o2; ov.w = o3;
        ((uint4*)st)[i] = ov;
      }
      __syncthreads();
      int h = lane >> 4, lm = lane & 15;
      short8 bfrag[4];
      #pragma unroll
      for (int kk = 0; kk < 4; ++kk)
        #pragma unroll
        for (int jj = 0; jj < 8; ++jj)
          bfrag[kk][jj] = (short)f2bf(Wz[(size_t)(kk * 32 + h * 8 + jj) * CP + lm]);
      const unsigned short* sb = stage + wv * 2176;
      short8 af[4];
      #pragma unroll
      for (int kk = 0; kk < 4; ++kk)
        af[kk] = *(const short8*)(sb + lm * 136 + kk * 32 + h * 8);
      f32x4 acc = {0.f, 0.f, 0.f, 0.f};
      #pragma unroll
      for (int kk = 0; kk < 4; ++kk)
        acc = __builtin_amdgcn_mfma_f32_16x16x32_bf16(af[kk], bfrag[kk], acc, 0, 0, 0);
      __syncthreads();
      #pragma unroll
      for (int jj = 0; jj < 4; ++jj)
        wlds[(wv * 16 + h * 4 + jj) * 16 + lm] = acc[jj];
    }
    __syncthreads();

    const float4* plm4 = (const float4*)plm;
    float4* out4 = (float4*)(out + (size_t)NA * CA);
    const int ntask = (E - S) * 4;
    for (int a = s + slot; a < e; a += 2) {
      size_t rowbase = ((size_t)a << 10);
      for (int base = 0; base < ntask; base += 1024) {
        float4 pv[4], wv4[4];
        size_t idx4[4];
        bool act[4];
        #pragma unroll
        for (int j = 0; j < 4; ++j) {
          int task = base + j * 256 + tid;
          act[j] = (task < ntask);
          int tt = act[j] ? task : 0;
          int b = S + (tt >> 2), quar = tt & 3;
          int m = ((int)tokL[b] - m0) & 63;
          idx4[j] = (rowbase + b) * 4 + quar;
          wv4[j] = *(const float4*)(wlds + m * 16 + quar * 4);
          pv[j]  = plm4[idx4[j]];
        }
        #pragma unroll
        for (int j = 0; j < 4; ++j) {
          if (act[j]) {
            float4 ov;
            ov.x = pv[j].x + wv4[j].x; ov.y = pv[j].y + wv4[j].y;
            ov.z = pv[j].z + wv4[j].z; ov.w = pv[j].w + wv4[j].w;
            out4[idx4[j]] = ov;
          }
        }
      }
    }
  } else if (blk < 2560) {
    int idx = (blk - 2048) * 256 + tid;
    int a = idx >> 7, j = idx & 127;
    int ta = (int)tok16[a] & 255;
    out[idx] = cl[idx] + bfu(ytok[(size_t)ta * CA + j]);
  } else {
    int idx = (blk - 2560) * 256 + tid;
    int a = idx >> 7, j = idx & 127;
    float r0 = rl[a * 3 + 0], r1 = rl[a * 3 + 1], r2 = rl[a * 3 + 2];
    float v = ql[idx];
    v = fmaf(r0, Wr[j], v);
    v = fmaf(r1, Wr[CA + j], v);
    v = fmaf(r2, Wr[2 * CA + j], v);
    out[(size_t)NA * CA + (size_t)NA * NA * CP + idx] = v;
  }
}

extern "C" void kernel_launch(void* const* d_in, const int* in_sizes, int n_in,
                              void* d_out, int out_size, void* d_ws, size_t ws_size,
                              hipStream_t stream) {
  const float* a2t     = (const float*)d_in[0];
  const float* cl      = (const float*)d_in[1];
  const float* plm     = (const float*)d_in[2];
  const float* ql      = (const float*)d_in[3];
  const float* s_trunk = (const float*)d_in[4];
  const float* zij     = (const float*)d_in[5];
  const float* rl      = (const float*)d_in[6];
  const float* lnsw    = (const float*)d_in[7];
  const float* lnsb    = (const float*)d_in[8];
  const float* Ws      = (const float*)d_in[9];
  const float* lnzw    = (const float*)d_in[10];
  const float* lnzb    = (const float*)d_in[11];
  const float* Wz      = (const float*)d_in[12];
  const float* Wr      = (const float*)d_in[13];
  float* out = (float*)d_out;

  // ws layout: tok16 @0 (2048 B) | ytok @2048 (65536 B) | wtm @67584 (2 MB)
  unsigned short* tok16 = (unsigned short*)d_ws;
  unsigned short* ytok  = (unsigned short*)((char*)d_ws + 2048);
  unsigned short* wtm   = (unsigned short*)((char*)d_ws + 67584);
  const size_t WS_NEEDED_A = 67584 + (size_t)NT * NT * CP * 2;  // 2,164,736 B

  if (ws_size >= WS_NEEDED_A) {
    // PATH A: materialize w_tm, pure streaming plm pass
    prep_full_kernel<<<1536, 256, 0, stream>>>(a2t, s_trunk, lnsw, lnsb, Ws,
                                               zij, lnzw, lnzb, Wz,
                                               tok16, ytok, wtm);
    stream_kernel<<<2304, 256, 0, stream>>>(cl, plm, ql, rl, Wr,
                                            tok16, ytok, wtm, out);
  } else {
    // PATH B: proven small-ws fallback (Round 4)
    prep_kernel<<<512, 256, 0, stream>>>(a2t, s_trunk, lnsw, lnsb, Ws, tok16, ytok);
    main_kernel<<<3072, 256, 0, stream>>>(cl, plm, ql, rl, Wr, zij, lnzw, lnzb, Wz,
                                          tok16, ytok, out);
  }
}

// Round 6
// 182.469 us; speedup vs baseline: 1.0280x; 1.0280x over previous
//
#include <hip/hip_runtime.h>
#include <hip/hip_bf16.h>

// Problem constants
#define NA 1024   // n_atom
#define NT 256    // n_token
#define CS 384    // c_s
#define CZ 128    // c_z
#define CA 128    // c_atom
#define CP 16     // c_atom_pair

typedef __attribute__((ext_vector_type(8))) short short8;
typedef __attribute__((ext_vector_type(4))) float f32x4;
typedef __attribute__((ext_vector_type(4))) unsigned int u32x4;

__device__ __forceinline__ float bflo(unsigned u){ return __uint_as_float(u << 16); }
__device__ __forceinline__ float bfhi(unsigned u){ return __uint_as_float(u & 0xffff0000u); }
__device__ __forceinline__ float bfu(unsigned short v){ return __uint_as_float(((unsigned)v) << 16); }
__device__ __forceinline__ unsigned short f2bf(float f){
  unsigned u = __float_as_uint(f);
  return (unsigned short)((u + 0x7fffu + ((u >> 16) & 1u)) >> 16); // RNE
}
__device__ __forceinline__ unsigned pack2(float lo, float hi){
  return (unsigned)f2bf(lo) | ((unsigned)f2bf(hi) << 16);
}

__device__ __forceinline__ int lbound(const unsigned short* tokL, int key){
  int lo = 0, hi = NA;
  while (lo < hi) { int mid = (lo + hi) >> 1; if ((int)tokL[mid] < key) lo = mid + 1; else hi = mid; }
  return lo;
}

// ===========================================================================
// PATH A (ws_size >= 2,164,736 B): materialize w_tm, then pure streaming pass.
// ws layout: tok16 [1024 u16]   bytes [0, 2048)
//            ytok  [32768 bf16]  bytes [2048, 67584)
//            w_tm  [1048576 bf16] bytes [67584, 2164736)
// R8: no nontemporal hints — harness keeps plm/out L2/L3-hot.
// R9: lane-major chunk mapping (unit-stride 1-KB wave segments). WIN (~4 µs).
// R10: 8 chunks/thread + tok16 LDS slice — NULL.
// R11: wtm row staged in LDS — NULL/worse (atoms sorted by token -> global
// gather was already near-sequential; LDS stage added a barrier for nothing).
// R12: copy-shape (2048 persistent blocks, all loads before stores) — WORSE
// (fewer blocks -> occupancy ramp/tail dominates; 4096 shallow blocks win).
// R13: REVERT to the R9 structure (measured best, 183.9 µs total). Four
// structural families converged at 38-45 µs for stream vs ~21 µs byte-floor;
// VALUBusy ~3%, zero bank conflicts, all access patterns coalesced. This is
// the achievable mixed-RMW-stream rate in this harness state; the measured
// total is dominated by fixed harness re-poison (266 MB fill @ 6.6 TB/s).
// R14: resubmit of R13 unchanged — previous round failed on container infra,
// not on the kernel (this source passed at 183.9 µs in Round 1).
// ===========================================================================

// prep_full: blocks [0,256)    role A: tok16[a] (wave per atom)
//            blocks [256,512)  role B: ytok[t,:] = LN_s(s_trunk[t])@W_s (bf16)
//            blocks [512,1536) role C: w_tm[t,m,:] = LN_z(zij[t,m])@W_z (bf16, MFMA)
__global__ __launch_bounds__(256) void prep_full_kernel(
    const float* __restrict__ a2t,
    const float* __restrict__ s_trunk,
    const float* __restrict__ lnsw,
    const float* __restrict__ lnsb,
    const float* __restrict__ Ws,
    const float* __restrict__ zij,
    const float* __restrict__ lnzw,
    const float* __restrict__ lnzb,
    const float* __restrict__ Wz,
    unsigned short* __restrict__ tok16,
    unsigned short* __restrict__ ytok,
    unsigned short* __restrict__ wtm)
{
  __shared__ float redS[4], redQ[4];
  __shared__ float lnbuf[CS];
  __shared__ float part[CA];
  __shared__ __align__(16) unsigned short stage[4 * 16 * 136]; // 17.4 KB

  const int blk  = blockIdx.x;
  const int tid  = threadIdx.x;
  const int lane = tid & 63;
  const int wv   = tid >> 6;

  if (blk < 256) {
    // ---- role A ----
    int a = blk * 4 + wv;
    float4 u = ((const float4*)(a2t + (size_t)a * NT))[lane];
    bool hit = (u.x != 0.f) | (u.y != 0.f) | (u.z != 0.f) | (u.w != 0.f);
    unsigned long long m = __ballot(hit);
    int fl = __ffsll(m) - 1;
    if (lane == fl) {
      int t = lane * 4;
      if (u.x != 0.f)      { }
      else if (u.y != 0.f) t += 1;
      else if (u.z != 0.f) t += 2;
      else                 t += 3;
      tok16[a] = (unsigned short)t;
    }
  } else if (blk < 512) {
    // ---- role B ----
    int tk = blk - 256;
    float f0 = 0.f, f1 = 0.f;
    if (tid < 192) {
      float2 v = ((const float2*)(s_trunk + (size_t)tk * CS))[tid];
      f0 = v.x; f1 = v.y;
    }
    float s = f0 + f1;
    float q = f0 * f0 + f1 * f1;
    #pragma unroll
    for (int m = 1; m < 64; m <<= 1) { s += __shfl_xor(s, m); q += __shfl_xor(q, m); }
    if (lane == 0) { redS[wv] = s; redQ[wv] = q; }
    __syncthreads();
    if (tid == 0) {
      float S = redS[0] + redS[1] + redS[2] + redS[3];
      float Q = redQ[0] + redQ[1] + redQ[2] + redQ[3];
      float mean = S * (1.f / 384.f);
      float var  = Q * (1.f / 384.f) - mean * mean;
      redS[0] = mean;
      redQ[0] = rsqrtf(var + 1e-5f);
    }
    __syncthreads();
    float mean = redS[0], rstd = redQ[0];
    if (tid < 192) {
      float2 w2 = ((const float2*)lnsw)[tid];
      float2 b2 = ((const float2*)lnsb)[tid];
      lnbuf[2 * tid]     = fmaf((f0 - mean) * rstd, w2.x, b2.x);
      lnbuf[2 * tid + 1] = fmaf((f1 - mean) * rstd, w2.y, b2.y);
    }
    __syncthreads();
    int j = tid & 127, half = tid >> 7;
    float acc = 0.f;
    int c0 = half * 192;
    #pragma unroll 8
    for (int c = c0; c < c0 + 192; ++c)
      acc = fmaf(lnbuf[c], Ws[(size_t)c * CA + j], acc);
    if (half) part[j] = acc;
    __syncthreads();
    if (!half) ytok[(size_t)tk * CA + j] = f2bf(acc + part[j]);
  } else {
    // ---- role C: wave = 16 rows of the 65536 (t*256+m) rows ----
    int cb = blk - 512;
    int r = lane >> 2, q = lane & 3;       // 4 lanes per row, 32 channels each
    int rowbase = cb * 64 + wv * 16;
    const float4* zp = (const float4*)(zij + (size_t)(rowbase + r) * CZ + q * 32);
    float x[32];
    float sm = 0.f, ss = 0.f;
    #pragma unroll
    for (int i = 0; i < 8; ++i) {
      float4 v = zp[i];
      x[4 * i]     = v.x; x[4 * i + 1] = v.y;
      x[4 * i + 2] = v.z; x[4 * i + 3] = v.w;
      sm += (v.x + v.y) + (v.z + v.w);
      ss = fmaf(v.x, v.x, ss); ss = fmaf(v.y, v.y, ss);
      ss = fmaf(v.z, v.z, ss); ss = fmaf(v.w, v.w, ss);
    }
    sm += __shfl_xor(sm, 1); sm += __shfl_xor(sm, 2);
    ss += __shfl_xor(ss, 1); ss += __shfl_xor(ss, 2);
    float mean = sm * (1.f / 128.f);
    float var  = ss * (1.f / 128.f) - mean * mean;
    float rstd = rsqrtf(var + 1e-5f);
    unsigned short* st = stage + wv * 2176 + r * 136 + q * 32;
    const float4* lwp = (const float4*)(lnzw + q * 32);
    const float4* lbp = (const float4*)(lnzb + q * 32);
    #pragma unroll
    for (int i = 0; i < 4; ++i) {
      float4 lw0 = lwp[2 * i], lw1 = lwp[2 * i + 1];
      float4 lb0 = lbp[2 * i], lb1 = lbp[2 * i + 1];
      int c = i * 8;
      unsigned o0 = pack2(fmaf((x[c]     - mean) * rstd, lw0.x, lb0.x),
                          fmaf((x[c + 1] - mean) * rstd, lw0.y, lb0.y));
      unsigned o1 = pack2(fmaf((x[c + 2] - mean) * rstd, lw0.z, lb0.z),
                          fmaf((x[c + 3] - mean) * rstd, lw0.w, lb0.w));
      unsigned o2 = pack2(fmaf((x[c + 4] - mean) * rstd, lw1.x, lb1.x),
                          fmaf((x[c + 5] - mean) * rstd, lw1.y, lb1.y));
      unsigned o3 = pack2(fmaf((x[c + 6] - mean) * rstd, lw1.z, lb1.z),
                          fmaf((x[c + 7] - mean) * rstd, lw1.w, lb1.w));
      uint4 ov; ov.x = o0; ov.y = o1; ov.z = o2; ov.w = o3;
      ((uint4*)st)[i] = ov;
    }
    __syncthreads();
    // B fragment: B[k][n], n = lane&15, k = kk*32 + (lane>>4)*8 + j
    int h = lane >> 4, lm = lane & 15;
    short8 bfrag[4];
    #pragma unroll
    for (int kk = 0; kk < 4; ++kk)
      #pragma unroll
      for (int jj = 0; jj < 8; ++jj)
        bfrag[kk][jj] = (short)f2bf(Wz[(size_t)(kk * 32 + h * 8 + jj) * CP + lm]);
    const unsigned short* sb = stage + wv * 2176;
    f32x4 acc = {0.f, 0.f, 0.f, 0.f};
    #pragma unroll
    for (int kk = 0; kk < 4; ++kk) {
      short8 af = *(const short8*)(sb + lm * 136 + kk * 32 + h * 8); // A[m=lm][k]
      acc = __builtin_amdgcn_mfma_f32_16x16x32_bf16(af, bfrag[kk], acc, 0, 0, 0);
    }
    // C/D: col(n)=lane&15, row(m)=(lane>>4)*4+reg
    #pragma unroll
    for (int jj = 0; jj < 4; ++jj)
      wtm[(size_t)(rowbase + h * 4 + jj) * CP + lm] = f2bf(acc[jj]);
  }
}

// stream (R9 structure, measured best):
//   blocks [0,4096)    pair part, lane-major: block covers 256 pairs (16 KB
//                      plm). thread t handles f32x4 chunk blk*1024 + t + 256j,
//                      j=0..3 (unit-stride 1-KB wave segments). Addend: one
//                      8-B global gather per chunk; lanes 4k..4k+3 cover one
//                      contiguous 32-B wtm row, and tok16 being sorted makes
//                      consecutive groups' rows ascend -> near-sequential.
//   blocks [4096,4224) cl_out = cl + ytok[tok[a]]   (f32x4/thread)
//   blocks [4224,4352) ql_out = ql + rl @ W_r       (f32x4/thread)
__global__ __launch_bounds__(256) void stream_kernel(
    const float* __restrict__ cl,
    const float* __restrict__ plm,
    const float* __restrict__ ql,
    const float* __restrict__ rl,
    const float* __restrict__ Wr,
    const unsigned short* __restrict__ tok16,
    const unsigned short* __restrict__ ytok,
    const unsigned short* __restrict__ wtm,
    float* __restrict__ out)
{
  const int blk = blockIdx.x;
  const int tid = threadIdx.x;
  if (blk < 4096) {
    // block-uniform atom a -> scalar ta; w panel base for this a
    const int a  = blk >> 2;
    const int ta = (int)tok16[a];
    const int b0 = (blk & 3) * 256;
    const int quar = tid & 3;       // which f32x4 quarter of the 16-ch pair row
    const int pl   = tid >> 2;      // local pair within 64-pair group
    const unsigned short* wrow = wtm + ((size_t)ta << 12);   // ta*256*16 bf16
    const f32x4* pp = (const f32x4*)plm + (size_t)blk * 1024 + tid;
    f32x4* op = (f32x4*)(out + (size_t)NA * CA) + (size_t)blk * 1024 + tid;
    uint2 w_[4];
    f32x4 p_[4];
    #pragma unroll
    for (int j = 0; j < 4; ++j) {
      int b  = b0 + pl + 64 * j;
      int tb = (int)tok16[b];
      // 8-B gather; lanes 4k..4k+3 together read one contiguous 32-B row
      w_[j] = *(const uint2*)(wrow + tb * CP + quar * 4);
      p_[j] = pp[256 * j];
    }
    #pragma unroll
    for (int j = 0; j < 4; ++j) {
      f32x4 o;
      o.x = p_[j].x + bflo(w_[j].x);
      o.y = p_[j].y + bfhi(w_[j].x);
      o.z = p_[j].z + bflo(w_[j].y);
      o.w = p_[j].w + bfhi(w_[j].y);
      op[256 * j] = o;
    }
  } else if (blk < 4224) {
    // cl: 32768 f32x4 chunks
    int c = (blk - 4096) * 256 + tid;
    int aa = c >> 5, jq = c & 31;
    int ta = (int)tok16[aa];
    uint2 y = *(const uint2*)(ytok + (size_t)ta * CA + jq * 4);
    f32x4 v = ((const f32x4*)cl)[c];
    f32x4 o;
    o.x = v.x + bflo(y.x); o.y = v.y + bfhi(y.x);
    o.z = v.z + bflo(y.y); o.w = v.w + bfhi(y.y);
    ((f32x4*)out)[c] = o;
  } else {
    // ql: 32768 f32x4 chunks
    int c = (blk - 4224) * 256 + tid;
    int aa = c >> 5, j0 = (c & 31) * 4;
    float r0 = rl[aa * 3 + 0], r1 = rl[aa * 3 + 1], r2 = rl[aa * 3 + 2];
    f32x4 w0 = *(const f32x4*)(Wr + j0);
    f32x4 w1 = *(const f32x4*)(Wr + CA + j0);
    f32x4 w2 = *(const f32x4*)(Wr + 2 * CA + j0);
    f32x4 v = ((const f32x4*)ql)[c];
    f32x4 o;
    o.x = fmaf(r2, w2.x, fmaf(r1, w1.x, fmaf(r0, w0.x, v.x)));
    o.y = fmaf(r2, w2.y, fmaf(r1, w1.y, fmaf(r0, w0.y, v.y)));
    o.z = fmaf(r2, w2.z, fmaf(r1, w1.z, fmaf(r0, w0.z, v.z)));
    o.w = fmaf(r2, w2.w, fmaf(r1, w1.w, fmaf(r0, w0.w, v.w)));
    ((f32x4*)out)[((size_t)NA * CA + (size_t)NA * NA * CP) / 4 + c] = o;
  }
}

// ===========================================================================
// PATH B (fallback, small ws): Round-4 kernels, proven correct at 66 KB ws.
// ===========================================================================
__global__ __launch_bounds__(256) void prep_kernel(
    const float* __restrict__ a2t,
    const float* __restrict__ s_trunk,
    const float* __restrict__ lnsw,
    const float* __restrict__ lnsb,
    const float* __restrict__ Ws,
    unsigned short* __restrict__ tok16,
    unsigned short* __restrict__ ytok)
{
  __shared__ float redS[4], redQ[4];
  __shared__ float lnbuf[CS];
  __shared__ float part[CA];

  const int blk  = blockIdx.x;
  const int tid  = threadIdx.x;
  const int lane = tid & 63;
  const int wv   = tid >> 6;

  if (blk < 256) {
    int a = blk * 4 + wv;
    float4 u = ((const float4*)(a2t + (size_t)a * NT))[lane];
    bool hit = (u.x != 0.f) | (u.y != 0.f) | (u.z != 0.f) | (u.w != 0.f);
    unsigned long long m = __ballot(hit);
    int fl = __ffsll(m) - 1;
    if (lane == fl) {
      int t = lane * 4;
      if (u.x != 0.f)      { }
      else if (u.y != 0.f) t += 1;
      else if (u.z != 0.f) t += 2;
      else                 t += 3;
      tok16[a] = (unsigned short)t;
    }
  } else {
    int tk = blk - 256;
    float f0 = 0.f, f1 = 0.f;
    if (tid < 192) {
      float2 v = ((const float2*)(s_trunk + (size_t)tk * CS))[tid];
      f0 = v.x; f1 = v.y;
    }
    float s = f0 + f1;
    float q = f0 * f0 + f1 * f1;
    #pragma unroll
    for (int m = 1; m < 64; m <<= 1) { s += __shfl_xor(s, m); q += __shfl_xor(q, m); }
    if (lane == 0) { redS[wv] = s; redQ[wv] = q; }
    __syncthreads();
    if (tid == 0) {
      float S = redS[0] + redS[1] + redS[2] + redS[3];
      float Q = redQ[0] + redQ[1] + redQ[2] + redQ[3];
      float mean = S * (1.f / 384.f);
      float var  = Q * (1.f / 384.f) - mean * mean;
      redS[0] = mean;
      redQ[0] = rsqrtf(var + 1e-5f);
    }
    __syncthreads();
    float mean = redS[0], rstd = redQ[0];
    if (tid < 192) {
      float2 w2 = ((const float2*)lnsw)[tid];
      float2 b2 = ((const float2*)lnsb)[tid];
      lnbuf[2 * tid]     = fmaf((f0 - mean) * rstd, w2.x, b2.x);
      lnbuf[2 * tid + 1] = fmaf((f1 - mean) * rstd, w2.y, b2.y);
    }
    __syncthreads();
    int j = tid & 127, half = tid >> 7;
    float acc = 0.f;
    int c0 = half * 192;
    #pragma unroll 8
    for (int c = c0; c < c0 + 192; ++c)
      acc = fmaf(lnbuf[c], Ws[(size_t)c * CA + j], acc);
    if (half) part[j] = acc;
    __syncthreads();
    if (!half) ytok[(size_t)tk * CA + j] = f2bf(acc + part[j]);
  }
}

__global__ __launch_bounds__(256) void main_kernel(
    const float* __restrict__ cl,
    const float* __restrict__ plm,
    const float* __restrict__ ql,
    const float* __restrict__ rl,
    const float* __restrict__ Wr,
    const float* __restrict__ zij,
    const float* __restrict__ lnzw,
    const float* __restrict__ lnzb,
    const float* __restrict__ Wz,
    const unsigned short* __restrict__ tok16,
    const unsigned short* __restrict__ ytok,
    float* __restrict__ out)
{
  const int blk = blockIdx.x;
  const int tid = threadIdx.x;

  if (blk < 2048) {
    __shared__ unsigned short tokL[NA];
    __shared__ __align__(16) unsigned short ubuf[4 * 16 * 136];
    unsigned short* stage = ubuf;
    float* wlds = (float*)ubuf;

    const int lane = tid & 63;
    const int wv   = tid >> 6;
    const int t    = blk >> 3;
    const int m0   = ((blk >> 1) & 3) << 6;
    const int slot = blk & 1;

    ((uint2*)tokL)[tid] = ((const uint2*)tok16)[tid];
    __syncthreads();

    int s = lbound(tokL, t);
    int e = lbound(tokL, t + 1);
    if (s + slot >= e) return;
    int S = lbound(tokL, m0);
    int E = lbound(tokL, m0 + 64);
    if (S == E) return;

    {
      int r = lane >> 2, q = lane & 3;
      int mrow = m0 + wv * 16 + r;
      const float4* zp = (const float4*)(zij + ((size_t)t * NT + mrow) * CZ + q * 32);
      float x[32];
      float sm = 0.f, ss = 0.f;
      #pragma unroll
      for (int i = 0; i < 8; ++i) {
        float4 v = zp[i];
        x[4 * i]     = v.x; x[4 * i + 1] = v.y;
        x[4 * i + 2] = v.z; x[4 * i + 3] = v.w;
        sm += (v.x + v.y) + (v.z + v.w);
        ss = fmaf(v.x, v.x, ss); ss = fmaf(v.y, v.y, ss);
        ss = fmaf(v.z, v.z, ss); ss = fmaf(v.w, v.w, ss);
      }
      sm += __shfl_xor(sm, 1); sm += __shfl_xor(sm, 2);
      ss += __shfl_xor(ss, 1); ss += __shfl_xor(ss, 2);
      float mean = sm * (1.f / 128.f);
      float var  = ss * (1.f / 128.f) - mean * mean;
      float rstd = rsqrtf(var + 1e-5f);
      unsigned short* st = stage + wv * 2176 + r * 136 + q * 32;
      const float4* lwp = (const float4*)(lnzw + q * 32);
      const float4* lbp = (const float4*)(lnzb + q * 32);
      #pragma unroll
      for (int i = 0; i < 4; ++i) {
        float4 lw0 = lwp[2 * i], lw1 = lwp[2 * i + 1];
        float4 lb0 = lbp[2 * i], lb1 = lbp[2 * i + 1];
        int c = i * 8;
        unsigned o0 = pack2(fmaf((x[c]     - mean) * rstd, lw0.x, lb0.x),
                            fmaf((x[c + 1] - mean) * rstd, lw0.y, lb0.y));
        unsigned o1 = pack2(fmaf((x[c + 2] - mean) * rstd, lw0.z, lb0.z),
                            fmaf((x[c + 3] - mean) * rstd, lw0.w, lb0.w));
        unsigned o2 = pack2(fmaf((x[c + 4] - mean) * rstd, lw1.x, lb1.x),
                            fmaf((x[c + 5] - mean) * rstd, lw1.y, lb1.y));
        unsigned o3 = pack2(fmaf((x[c + 6] - mean) * rstd, lw1.z, lb1.z),
                            fmaf((x[c + 7] - mean) * rstd, lw1.w, lb1.w));
        uint4 ov; ov.x = o0; ov.y = o1; ov.z = o2; ov.w = o3;
        ((uint4*)st)[i] = ov;
      }
      __syncthreads();
      int h = lane >> 4, lm = lane & 15;
      short8 bfrag[4];
      #pragma unroll
      for (int kk = 0; kk < 4; ++kk)
        #pragma unroll
        for (int jj = 0; jj < 8; ++jj)
          bfrag[kk][jj] = (short)f2bf(Wz[(size_t)(kk * 32 + h * 8 + jj) * CP + lm]);
      const unsigned short* sb = stage + wv * 2176;
      short8 af[4];
      #pragma unroll
      for (int kk = 0; kk < 4; ++kk)
        af[kk] = *(const short8*)(sb + lm * 136 + kk * 32 + h * 8);
      f32x4 acc = {0.f, 0.f, 0.f, 0.f};
      #pragma unroll
      for (int kk = 0; kk < 4; ++kk)
        acc = __builtin_amdgcn_mfma_f32_16x16x32_bf16(af[kk], bfrag[kk], acc, 0, 0, 0);
      __syncthreads();
      #pragma unroll
      for (int jj = 0; jj < 4; ++jj)
        wlds[(wv * 16 + h * 4 + jj) * 16 + lm] = acc[jj];
    }
    __syncthreads();

    const float4* plm4 = (const float4*)plm;
    float4* out4 = (float4*)(out + (size_t)NA * CA);
    const int ntask = (E - S) * 4;
    for (int a = s + slot; a < e; a += 2) {
      size_t rowbase = ((size_t)a << 10);
      for (int base = 0; base < ntask; base += 1024) {
        float4 pv[4], wv4[4];
        size_t idx4[4];
        bool act[4];
        #pragma unroll
        for (int j = 0; j < 4; ++j) {
          int task = base + j * 256 + tid;
          act[j] = (task < ntask);
          int tt = act[j] ? task : 0;
          int b = S + (tt >> 2), quar = tt & 3;
          int m = ((int)tokL[b] - m0) & 63;
          idx4[j] = (rowbase + b) * 4 + quar;
          wv4[j] = *(const float4*)(wlds + m * 16 + quar * 4);
          pv[j]  = plm4[idx4[j]];
        }
        #pragma unroll
        for (int j = 0; j < 4; ++j) {
          if (act[j]) {
            float4 ov;
            ov.x = pv[j].x + wv4[j].x; ov.y = pv[j].y + wv4[j].y;
            ov.z = pv[j].z + wv4[j].z; ov.w = pv[j].w + wv4[j].w;
            out4[idx4[j]] = ov;
          }
        }
      }
    }
  } else if (blk < 2560) {
    int idx = (blk - 2048) * 256 + tid;
    int a = idx >> 7, j = idx & 127;
    int ta = (int)tok16[a] & 255;
    out[idx] = cl[idx] + bfu(ytok[(size_t)ta * CA + j]);
  } else {
    int idx = (blk - 2560) * 256 + tid;
    int a = idx >> 7, j = idx & 127;
    float r0 = rl[a * 3 + 0], r1 = rl[a * 3 + 1], r2 = rl[a * 3 + 2];
    float v = ql[idx];
    v = fmaf(r0, Wr[j], v);
    v = fmaf(r1, Wr[CA + j], v);
    v = fmaf(r2, Wr[2 * CA + j], v);
    out[(size_t)NA * CA + (size_t)NA * NA * CP + idx] = v;
  }
}

extern "C" void kernel_launch(void* const* d_in, const int* in_sizes, int n_in,
                              void* d_out, int out_size, void* d_ws, size_t ws_size,
                              hipStream_t stream) {
  const float* a2t     = (const float*)d_in[0];
  const float* cl      = (const float*)d_in[1];
  const float* plm     = (const float*)d_in[2];
  const float* ql      = (const float*)d_in[3];
  const float* s_trunk = (const float*)d_in[4];
  const float* zij     = (const float*)d_in[5];
  const float* rl      = (const float*)d_in[6];
  const float* lnsw    = (const float*)d_in[7];
  const float* lnsb    = (const float*)d_in[8];
  const float* Ws      = (const float*)d_in[9];
  const float* lnzw    = (const float*)d_in[10];
  const float* lnzb    = (const float*)d_in[11];
  const float* Wz      = (const float*)d_in[12];
  const float* Wr      = (const float*)d_in[13];
  float* out = (float*)d_out;

  // ws layout: tok16 @0 (2048 B) | ytok @2048 (65536 B) | wtm @67584 (2 MB)
  unsigned short* tok16 = (unsigned short*)d_ws;
  unsigned short* ytok  = (unsigned short*)((char*)d_ws + 2048);
  unsigned short* wtm   = (unsigned short*)((char*)d_ws + 67584);
  const size_t WS_NEEDED_A = 67584 + (size_t)NT * NT * CP * 2;  // 2,164,736 B

  if (ws_size >= WS_NEEDED_A) {
    // PATH A: materialize w_tm, pure streaming plm pass
    prep_full_kernel<<<1536, 256, 0, stream>>>(a2t, s_trunk, lnsw, lnsb, Ws,
                                               zij, lnzw, lnzb, Wz,
                                               tok16, ytok, wtm);
    stream_kernel<<<4352, 256, 0, stream>>>(cl, plm, ql, rl, Wr,
                                            tok16, ytok, wtm, out);
  } else {
    // PATH B: proven small-ws fallback (Round 4)
    prep_kernel<<<512, 256, 0, stream>>>(a2t, s_trunk, lnsw, lnsb, Ws, tok16, ytok);
    main_kernel<<<3072, 256, 0, stream>>>(cl, plm, ql, rl, Wr, zij, lnzw, lnzb, Wz,
                                          tok16, ytok, out);
  }
}